// Round 17
// baseline (97.074 us; speedup 1.0000x reference)
//
#include <hip/hip_runtime.h>
#include <hip/hip_bf16.h>
#include <math.h>

// CausalFullAttention: out[b,l,h,d] = softmax_s( 0.125*(q.k + bias[l,s]), s<=l ) @ V
// B=4 L=S=2048 H=8 E=D=64, fp32 in/out, bf16 MFMA compute.
// R16: KV-split + merge. 1024 blocks = (32 bh x 16 qp x 2 kv-halves), each = R14
//      structure (2 LDS buffers, 1 barrier/tile, K-perm direct-pack softmax) over
//      max 16 tiles -> uniform short blocks, 3 blocks/CU TLP. Partial (O,m,l) in
//      d_ws; second kernel merges. Host falls back to R15-style single kernel if
//      ws_size is too small.

typedef __bf16 bf16x8 __attribute__((ext_vector_type(8)));
typedef __bf16 bf16x2 __attribute__((ext_vector_type(2)));
typedef float  f32x4  __attribute__((ext_vector_type(4)));
typedef unsigned int u32;
typedef u32 u32x4 __attribute__((ext_vector_type(4)));

#define NB 4
#define NL 2048
#define NS 2048
#define NH 8
#define NE 64
#define ND 64
#define OPH (NB * NL * NH * ND)    // floats per half O-partial: 4,194,304
#define MLH (NB * NL * NH)         // floats per half m/l: 65,536

__device__ __forceinline__ int swz(int d) { return ((d ^ (d >> 3)) & 7) << 3; }

__device__ __forceinline__ u32 cvtpk(float lo, float hi) {
    u32 r;
    asm("v_cvt_pk_bf16_f32 %0, %1, %2" : "=v"(r) : "v"(lo), "v"(hi));
    return r;
}
__device__ __forceinline__ float bpermf(int srclane, float v) {
    return __uint_as_float((u32)__builtin_amdgcn_ds_bpermute(srclane << 2, (int)__float_as_uint(v)));
}
__device__ __forceinline__ bf16x8 cvt8s(f32x4 a, f32x4 b, float sc) {
    bf16x8 r;
    r[0]=(__bf16)(a[0]*sc); r[1]=(__bf16)(a[1]*sc); r[2]=(__bf16)(a[2]*sc); r[3]=(__bf16)(a[3]*sc);
    r[4]=(__bf16)(b[0]*sc); r[5]=(__bf16)(b[1]*sc); r[6]=(__bf16)(b[2]*sc); r[7]=(__bf16)(b[3]*sc);
    return r;
}
__device__ __forceinline__ bf16x8 cvt8(f32x4 a, f32x4 b) {
    bf16x8 r;
    r[0]=(__bf16)a[0]; r[1]=(__bf16)a[1]; r[2]=(__bf16)a[2]; r[3]=(__bf16)a[3];
    r[4]=(__bf16)b[0]; r[5]=(__bf16)b[1]; r[6]=(__bf16)b[2]; r[7]=(__bf16)b[3];
    return r;
}

// ---------------- core body: tiles [t0, t1) of (b,h,qb); WRITE_WS selects sink ----
template<bool WRITE_WS>
__device__ __forceinline__ void fa_core(const float* __restrict__ Q,
                                        const float* __restrict__ K,
                                        const float* __restrict__ V,
                                        const float* __restrict__ Bias,
                                        float* __restrict__ OutOrO,
                                        float* __restrict__ Mp, float* __restrict__ Lp,
                                        int b, int h, int qb, int t0, int t1)
{
    __shared__ __bf16 Klds[2][64][72];   // K tile, ROW-PERMUTED
    __shared__ __bf16 Vlds[2][64][64];   // V^T tile, XOR slot swizzle

    const int tid  = threadIdx.x;
    const int w    = tid >> 6, lane = tid & 63;
    const int g    = lane >> 4, li = lane & 15;
    const int qw   = qb + (w << 4);

    const float SC = 0.125f * 1.44269504088896340736f;

    bf16x8 qa[2];
    {
        const float* qp = Q + (((size_t)(b * NL + qw + li)) * NH + h) * NE;
        #pragma unroll
        for (int eh = 0; eh < 2; ++eh) {
            const int e0 = eh * 32 + g * 8;
            f32x4 f0 = *(const f32x4*)(qp + e0);
            f32x4 f1 = *(const f32x4*)(qp + e0 + 4);
            qa[eh] = cvt8s(f0, f1, SC);
        }
    }

    f32x4 o[4] = {};
    float m_run = -INFINITY, l_run = 0.0f;

    const int nt = t1 - t0;

    const int skv = tid >> 3,        se0 = (tid & 7) << 3;
    const int vkv = (tid >> 4) << 1, vd0 = (tid & 15) << 2;
    const int rho = (skv & 32) | (((skv >> 2) & 1) << 4) | (((skv >> 3) & 3) << 2) | (skv & 3);

    const float* kp0 = K + (((size_t)(b * NS + skv)) * NH + h) * NE + se0;
    const float* vp0 = V + (((size_t)(b * NS + vkv)) * NH + h) * ND + vd0;
    const float* bp0 = Bias + (size_t)(qw + li) * NS + g * 8;

    f32x4 ka0, ka1, va0, va1;
    f32x4 bc[4], bn[4];

    auto issue_kv = [&](int T) {
        const float* kp = kp0 + (size_t)(T << 6) * (NH * NE);
        ka0 = ((const f32x4*)kp)[0]; ka1 = ((const f32x4*)kp)[1];
        const float* vp = vp0 + (size_t)(T << 6) * (NH * ND);
        va0 = *(const f32x4*)(vp); va1 = *(const f32x4*)(vp + NH * ND);
    };
    auto load_bias = [&](f32x4 (&bx)[4], int T) {
        const float* bp = bp0 + (T << 6);
        #pragma unroll
        for (int c = 0; c < 4; ++c)
            bx[c] = *(const f32x4*)(bp + ((c >> 1) << 5) + ((c & 1) << 2));
    };
    auto write_lds = [&](int buf) {
        *(bf16x8*)&Klds[buf][rho][se0] = cvt8(ka0, ka1);
        #pragma unroll
        for (int dd = 0; dd < 4; ++dd) {
            bf16x2 cc; cc[0] = (__bf16)va0[dd]; cc[1] = (__bf16)va1[dd];
            *(bf16x2*)&Vlds[buf][vd0 + dd][vkv ^ swz(vd0 + dd)] = cc;
        }
    };

    // prologue
    issue_kv(t0);
    load_bias(bc, t0);
    write_lds(0);
    if (nt > 1) issue_kv(t0 + 1);
    __syncthreads();

    for (int i = 0; i < nt; ++i) {
        const int t = t0 + i;
        const int cur = i & 1;
        const bool more = (i + 1 < nt);

        if (more) {
            load_bias(bn, t + 1);
            write_lds(cur ^ 1);
            if (i + 2 < nt) issue_kv(t + 2);
        }

        const int kv0 = t << 6;
        if (kv0 <= qw + 15) {
            f32x4 s[4];
            #pragma unroll
            for (int c = 0; c < 4; ++c) {
                f32x4 acc = {};
                #pragma unroll
                for (int eh = 0; eh < 2; ++eh) {
                    bf16x8 kb = *(const bf16x8*)&Klds[cur][c * 16 + li][eh * 32 + g * 8];
                    acc = __builtin_amdgcn_mfma_f32_16x16x32_bf16(kb, qa[eh], acc, 0, 0, 0);
                }
                s[c] = acc;
            }
            const int lg = qw + li;
            if (kv0 + 63 > qw) {
                #pragma unroll
                for (int c = 0; c < 4; ++c) {
                    const int kvb = kv0 + ((c >> 1) << 5) + (g << 3) + ((c & 1) << 2);
                    #pragma unroll
                    for (int r = 0; r < 4; ++r)
                        s[c][r] = (kvb + r <= lg) ? fmaf(bc[c][r], SC, s[c][r]) : -INFINITY;
                }
            } else {
                #pragma unroll
                for (int c = 0; c < 4; ++c)
                    #pragma unroll
                    for (int r = 0; r < 4; ++r)
                        s[c][r] = fmaf(bc[c][r], SC, s[c][r]);
            }
            float pm = fmaxf(
                fmaxf(fmaxf(fmaxf(s[0][0],s[0][1]),fmaxf(s[0][2],s[0][3])),
                      fmaxf(fmaxf(s[1][0],s[1][1]),fmaxf(s[1][2],s[1][3]))),
                fmaxf(fmaxf(fmaxf(s[2][0],s[2][1]),fmaxf(s[2][2],s[2][3])),
                      fmaxf(fmaxf(s[3][0],s[3][1]),fmaxf(s[3][2],s[3][3]))));
            pm = fmaxf(pm, __shfl_xor(pm, 16, 64));
            pm = fmaxf(pm, __shfl_xor(pm, 32, 64));
            if (!__all(pm <= m_run + 8.0f)) {
                const float mn = fmaxf(m_run, pm);
                const float corr = exp2f(m_run - mn);
                m_run = mn; l_run *= corr;
                #pragma unroll
                for (int j = 0; j < 4; ++j) {
                    const float cj = bpermf(g * 20 + j, corr);
                    o[0][j] *= cj; o[1][j] *= cj; o[2][j] *= cj; o[3][j] *= cj;
                }
            }
            #pragma unroll
            for (int c = 0; c < 4; ++c)
                #pragma unroll
                for (int r = 0; r < 4; ++r)
                    s[c][r] = exp2f(s[c][r] - m_run);
            float rs = ((s[0][0]+s[0][1])+(s[0][2]+s[0][3]))
                     + ((s[1][0]+s[1][1])+(s[1][2]+s[1][3]))
                     + ((s[2][0]+s[2][1])+(s[2][2]+s[2][3]))
                     + ((s[3][0]+s[3][1])+(s[3][2]+s[3][3]));
            rs += __shfl_xor(rs, 16, 64);
            rs += __shfl_xor(rs, 32, 64);
            l_run += rs;
            u32x4 pw0, pw1;
            pw0[0] = cvtpk(s[0][0], s[0][1]); pw0[1] = cvtpk(s[0][2], s[0][3]);
            pw0[2] = cvtpk(s[1][0], s[1][1]); pw0[3] = cvtpk(s[1][2], s[1][3]);
            pw1[0] = cvtpk(s[2][0], s[2][1]); pw1[1] = cvtpk(s[2][2], s[2][3]);
            pw1[2] = cvtpk(s[3][0], s[3][1]); pw1[3] = cvtpk(s[3][2], s[3][3]);
            const bf16x8 pa0 = __builtin_bit_cast(bf16x8, pw0);
            const bf16x8 pa1 = __builtin_bit_cast(bf16x8, pw1);
            #pragma unroll
            for (int dt = 0; dt < 4; ++dt) {
                const int d = dt * 16 + li;
                bf16x8 v0 = *(const bf16x8*)&Vlds[cur][d][(g * 8) ^ swz(d)];
                bf16x8 v1 = *(const bf16x8*)&Vlds[cur][d][(32 + g * 8) ^ swz(d)];
                o[dt] = __builtin_amdgcn_mfma_f32_16x16x32_bf16(pa0, v0, o[dt], 0, 0, 0);
                o[dt] = __builtin_amdgcn_mfma_f32_16x16x32_bf16(pa1, v1, o[dt], 0, 0, 0);
            }
        }

        if (more) {
            __syncthreads();
            #pragma unroll
            for (int c = 0; c < 4; ++c) bc[c] = bn[c];
        }
    }

    if (WRITE_WS) {
        // raw partial O + per-row m,l (log2 domain)
        #pragma unroll
        for (int j = 0; j < 4; ++j) {
            const int lgq = qw + g * 4 + j;
            float* op = OutOrO + (((size_t)(b * NL + lgq)) * NH + h) * ND + li;
            op[0]  = o[0][j];
            op[16] = o[1][j];
            op[32] = o[2][j];
            op[48] = o[3][j];
        }
        if (g == 0) {
            const size_t rh = ((size_t)(b * NL + qw + li)) * NH + h;
            Mp[rh] = m_run;
            Lp[rh] = l_run;
        }
    } else {
        #pragma unroll
        for (int j = 0; j < 4; ++j) {
            const float lj = bpermf(g * 20 + j, l_run);
            const float inv = 1.0f / lj;
            const int lgq = qw + g * 4 + j;
            float* op = OutOrO + (((size_t)(b * NL + lgq)) * NH + h) * ND + li;
            op[0]  = o[0][j] * inv;
            op[16] = o[1][j] * inv;
            op[32] = o[2][j] * inv;
            op[48] = o[3][j] * inv;
        }
    }
}

// ---------------- split kernel: 1024 blocks = 16 qp (desc) x 32 bh x 2 half ----
__global__ __launch_bounds__(512)
void fa_part(const float* __restrict__ Q, const float* __restrict__ K,
             const float* __restrict__ V, const float* __restrict__ Bias,
             float* __restrict__ Ws)
{
    const int id     = blockIdx.x;
    const int qp     = 15 - (id >> 6);        // heavy first
    const int j      = id & 63;
    const int bh     = j >> 1, half = j & 1;
    const int b      = bh >> 3, h = bh & 7;
    const int qb     = qp << 7;
    const int t0     = half ? (qp + 1) : 0;
    const int t1     = half ? (2 * qp + 2) : (qp + 1);

    float* Op = Ws + (size_t)half * OPH;
    float* Mp = Ws + 2 * (size_t)OPH + (size_t)half * MLH;
    float* Lp = Ws + 2 * (size_t)OPH + 2 * (size_t)MLH + (size_t)half * MLH;
    fa_core<true>(Q, K, V, Bias, Op, Mp, Lp, b, h, qb, t0, t1);
}

// ---------------- merge kernel: memory-bound combine of the two halves ----
__global__ __launch_bounds__(256)
void fa_merge(const float* __restrict__ Ws, float* __restrict__ Out)
{
    const int idx = blockIdx.x * 256 + threadIdx.x;   // 0 .. OPH-1
    const int rh  = idx >> 6;                          // row*NH+h index
    const float* Mp = Ws + 2 * (size_t)OPH;
    const float* Lp = Ws + 2 * (size_t)OPH + 2 * (size_t)MLH;
    const float m1 = Mp[rh], m2 = Mp[MLH + rh];
    const float l1 = Lp[rh], l2 = Lp[MLH + rh];
    const float mm = fmaxf(m1, m2);
    const float c1 = exp2f(m1 - mm), c2 = exp2f(m2 - mm);
    const float inv = 1.0f / (c1 * l1 + c2 * l2);
    Out[idx] = (c1 * Ws[idx] + c2 * Ws[OPH + idx]) * inv;
}

// ---------------- fallback: R15-equivalent single kernel (no ws needed) ----
__global__ __launch_bounds__(512)
void fa_fwd_single(const float* __restrict__ Q, const float* __restrict__ K,
                   const float* __restrict__ V, const float* __restrict__ Bias,
                   float* __restrict__ Out)
{
    const int id = blockIdx.x;
    int bh, qp_;
    if (id < 256) { bh = id >> 4;                qp_ = 15 - (id & 15); }
    else          { bh = 16 + ((id - 256) >> 4); qp_ = id & 15;        }
    const int b  = bh >> 3, h = bh & 7;
    const int qb = qp_ << 7;
    fa_core<false>(Q, K, V, Bias, Out, nullptr, nullptr, b, h, qb, 0, (qb >> 6) + 2);
}

extern "C" void kernel_launch(void* const* d_in, const int* in_sizes, int n_in,
                              void* d_out, int out_size, void* d_ws, size_t ws_size,
                              hipStream_t stream)
{
    const float* Q    = (const float*)d_in[0];
    const float* K    = (const float*)d_in[1];
    const float* V    = (const float*)d_in[2];
    const float* Bias = (const float*)d_in[3];
    float* Out = (float*)d_out;

    const size_t need = ((size_t)2 * OPH + 4 * (size_t)MLH) * sizeof(float);  // ~34.6 MB
    if (ws_size >= need) {
        float* Ws = (float*)d_ws;
        fa_part <<<dim3(1024), dim3(512), 0, stream>>>(Q, K, V, Bias, Ws);
        fa_merge<<<dim3(OPH / 256), dim3(256), 0, stream>>>(Ws, Out);
    } else {
        fa_fwd_single<<<dim3(512), dim3(512), 0, stream>>>(Q, K, V, Bias, Out);
    }
}

// Round 19
// 87.741 us; speedup vs baseline: 1.1064x; 1.1064x over previous
//
#include <hip/hip_runtime.h>
#include <hip/hip_bf16.h>
#include <math.h>

// CausalFullAttention: out[b,l,h,d] = softmax_s( 0.125*(q.k + bias[l,s]), s<=l ) @ V
// B=4 L=S=2048 H=8 E=D=64, fp32 in/out, bf16 MFMA compute.
// R17 (resubmit after infra failure): 4-wave (256-thr) blocks, QBLK=64, kv-segments
//      <=16 tiles -> VGPR<128 keeps 16 waves/CU = 4 INDEPENDENT blocks/CU.
//      1536 part blocks + vectorized merge; 2-slot ws layout (34.6MB).
//      Per-wave compute = R14 core (K-perm direct-pack softmax, defer-max).

typedef __bf16 bf16x8 __attribute__((ext_vector_type(8)));
typedef __bf16 bf16x4 __attribute__((ext_vector_type(4)));
typedef float  f32x4  __attribute__((ext_vector_type(4)));
typedef unsigned int u32;
typedef u32 u32x4 __attribute__((ext_vector_type(4)));

#define NB 4
#define NL 2048
#define NS 2048
#define NH 8
#define NE 64
#define ND 64
#define OPH (NB * NL * NH * ND)    // floats per O-partial slot: 4,194,304
#define MLH (NB * NL * NH)         // floats per m/l slot: 65,536

__device__ __forceinline__ int swz(int d) { return ((d ^ (d >> 3)) & 7) << 3; }

__device__ __forceinline__ u32 cvtpk(float lo, float hi) {
    u32 r;
    asm("v_cvt_pk_bf16_f32 %0, %1, %2" : "=v"(r) : "v"(lo), "v"(hi));
    return r;
}
__device__ __forceinline__ float bpermf(int srclane, float v) {
    return __uint_as_float((u32)__builtin_amdgcn_ds_bpermute(srclane << 2, (int)__float_as_uint(v)));
}
__device__ __forceinline__ bf16x8 cvt8s(f32x4 a, f32x4 b, float sc) {
    bf16x8 r;
    r[0]=(__bf16)(a[0]*sc); r[1]=(__bf16)(a[1]*sc); r[2]=(__bf16)(a[2]*sc); r[3]=(__bf16)(a[3]*sc);
    r[4]=(__bf16)(b[0]*sc); r[5]=(__bf16)(b[1]*sc); r[6]=(__bf16)(b[2]*sc); r[7]=(__bf16)(b[3]*sc);
    return r;
}
__device__ __forceinline__ bf16x8 cvt8(f32x4 a, f32x4 b) {
    bf16x8 r;
    r[0]=(__bf16)a[0]; r[1]=(__bf16)a[1]; r[2]=(__bf16)a[2]; r[3]=(__bf16)a[3];
    r[4]=(__bf16)b[0]; r[5]=(__bf16)b[1]; r[6]=(__bf16)b[2]; r[7]=(__bf16)b[3];
    return r;
}

// ---- core: 256 threads, 4 waves x 16 q-rows, tiles [t0,t1) of (b,h,qb) ----
template<bool WRITE_WS>
__device__ __forceinline__ void fa_core(const float* __restrict__ Q,
                                        const float* __restrict__ K,
                                        const float* __restrict__ V,
                                        const float* __restrict__ Bias,
                                        float* __restrict__ OutOrO,
                                        float* __restrict__ Mp, float* __restrict__ Lp,
                                        int b, int h, int qb, int t0, int t1)
{
    __shared__ __bf16 Klds[2][64][72];   // K tile, ROW-PERMUTED
    __shared__ __bf16 Vlds[2][64][64];   // V^T tile, XOR slot swizzle

    const int tid  = threadIdx.x;
    const int w    = tid >> 6, lane = tid & 63;
    const int g    = lane >> 4, li = lane & 15;
    const int qw   = qb + (w << 4);

    const float SC = 0.125f * 1.44269504088896340736f;

    bf16x8 qa[2];
    {
        const float* qp = Q + (((size_t)(b * NL + qw + li)) * NH + h) * NE;
        #pragma unroll
        for (int eh = 0; eh < 2; ++eh) {
            const int e0 = eh * 32 + g * 8;
            f32x4 f0 = *(const f32x4*)(qp + e0);
            f32x4 f1 = *(const f32x4*)(qp + e0 + 4);
            qa[eh] = cvt8s(f0, f1, SC);
        }
    }

    f32x4 o[4] = {};
    float m_run = -INFINITY, l_run = 0.0f;

    const int nt = t1 - t0;

    // 256-thread staging: K row/quarter; V 4kv x 4d sub-block
    const int skv = tid >> 2,        se0 = (tid & 3) << 4;
    const int vkv = (tid >> 4) << 2, vd0 = (tid & 15) << 2;
    const int rho = (skv & 32) | (((skv >> 2) & 1) << 4) | (((skv >> 3) & 3) << 2) | (skv & 3);

    const float* kp0 = K + (((size_t)(b * NS + skv)) * NH + h) * NE + se0;
    const float* vp0 = V + (((size_t)(b * NS + vkv)) * NH + h) * ND + vd0;
    const float* bp0 = Bias + (size_t)(qw + li) * NS + g * 8;

    f32x4 ka0, ka1, ka2, ka3, va0, va1, va2, va3;
    f32x4 bc[4], bn[4];

    auto issue_kv = [&](int T) {
        const float* kp = kp0 + (size_t)(T << 6) * (NH * NE);
        ka0 = ((const f32x4*)kp)[0]; ka1 = ((const f32x4*)kp)[1];
        ka2 = ((const f32x4*)kp)[2]; ka3 = ((const f32x4*)kp)[3];
        const float* vp = vp0 + (size_t)(T << 6) * (NH * ND);
        va0 = *(const f32x4*)(vp);
        va1 = *(const f32x4*)(vp + NH * ND);
        va2 = *(const f32x4*)(vp + 2 * NH * ND);
        va3 = *(const f32x4*)(vp + 3 * NH * ND);
    };
    auto load_bias = [&](f32x4 (&bx)[4], int T) {
        const float* bp = bp0 + (T << 6);
        #pragma unroll
        for (int c = 0; c < 4; ++c)
            bx[c] = *(const f32x4*)(bp + ((c >> 1) << 5) + ((c & 1) << 2));
    };
    auto write_lds = [&](int buf) {
        *(bf16x8*)&Klds[buf][rho][se0]     = cvt8(ka0, ka1);
        *(bf16x8*)&Klds[buf][rho][se0 + 8] = cvt8(ka2, ka3);
        bf16x4 cc;
        cc[0]=(__bf16)va0[0]; cc[1]=(__bf16)va1[0]; cc[2]=(__bf16)va2[0]; cc[3]=(__bf16)va3[0];
        *(bf16x4*)&Vlds[buf][vd0 + 0][vkv ^ swz(vd0 + 0)] = cc;
        cc[0]=(__bf16)va0[1]; cc[1]=(__bf16)va1[1]; cc[2]=(__bf16)va2[1]; cc[3]=(__bf16)va3[1];
        *(bf16x4*)&Vlds[buf][vd0 + 1][vkv ^ swz(vd0 + 1)] = cc;
        cc[0]=(__bf16)va0[2]; cc[1]=(__bf16)va1[2]; cc[2]=(__bf16)va2[2]; cc[3]=(__bf16)va3[2];
        *(bf16x4*)&Vlds[buf][vd0 + 2][vkv ^ swz(vd0 + 2)] = cc;
        cc[0]=(__bf16)va0[3]; cc[1]=(__bf16)va1[3]; cc[2]=(__bf16)va2[3]; cc[3]=(__bf16)va3[3];
        *(bf16x4*)&Vlds[buf][vd0 + 3][vkv ^ swz(vd0 + 3)] = cc;
    };

    // prologue
    issue_kv(t0);
    load_bias(bc, t0);
    write_lds(0);
    if (nt > 1) issue_kv(t0 + 1);
    __syncthreads();

    for (int i = 0; i < nt; ++i) {
        const int t = t0 + i;
        const int cur = i & 1;
        const bool more = (i + 1 < nt);

        if (more) {
            load_bias(bn, t + 1);
            write_lds(cur ^ 1);
            if (i + 2 < nt) issue_kv(t + 2);
        }

        const int kv0 = t << 6;
        if (kv0 <= qw + 15) {
            f32x4 s[4];
            #pragma unroll
            for (int c = 0; c < 4; ++c) {
                f32x4 acc = {};
                #pragma unroll
                for (int eh = 0; eh < 2; ++eh) {
                    bf16x8 kb = *(const bf16x8*)&Klds[cur][c * 16 + li][eh * 32 + g * 8];
                    acc = __builtin_amdgcn_mfma_f32_16x16x32_bf16(kb, qa[eh], acc, 0, 0, 0);
                }
                s[c] = acc;
            }
            const int lg = qw + li;
            if (kv0 + 63 > qw) {
                #pragma unroll
                for (int c = 0; c < 4; ++c) {
                    const int kvb = kv0 + ((c >> 1) << 5) + (g << 3) + ((c & 1) << 2);
                    #pragma unroll
                    for (int r = 0; r < 4; ++r)
                        s[c][r] = (kvb + r <= lg) ? fmaf(bc[c][r], SC, s[c][r]) : -INFINITY;
                }
            } else {
                #pragma unroll
                for (int c = 0; c < 4; ++c)
                    #pragma unroll
                    for (int r = 0; r < 4; ++r)
                        s[c][r] = fmaf(bc[c][r], SC, s[c][r]);
            }
            float pm = fmaxf(
                fmaxf(fmaxf(fmaxf(s[0][0],s[0][1]),fmaxf(s[0][2],s[0][3])),
                      fmaxf(fmaxf(s[1][0],s[1][1]),fmaxf(s[1][2],s[1][3]))),
                fmaxf(fmaxf(fmaxf(s[2][0],s[2][1]),fmaxf(s[2][2],s[2][3])),
                      fmaxf(fmaxf(s[3][0],s[3][1]),fmaxf(s[3][2],s[3][3]))));
            pm = fmaxf(pm, __shfl_xor(pm, 16, 64));
            pm = fmaxf(pm, __shfl_xor(pm, 32, 64));
            if (!__all(pm <= m_run + 8.0f)) {
                const float mn = fmaxf(m_run, pm);
                const float corr = exp2f(m_run - mn);
                m_run = mn; l_run *= corr;
                #pragma unroll
                for (int j = 0; j < 4; ++j) {
                    const float cj = bpermf(g * 20 + j, corr);
                    o[0][j] *= cj; o[1][j] *= cj; o[2][j] *= cj; o[3][j] *= cj;
                }
            }
            #pragma unroll
            for (int c = 0; c < 4; ++c)
                #pragma unroll
                for (int r = 0; r < 4; ++r)
                    s[c][r] = exp2f(s[c][r] - m_run);
            float rs = ((s[0][0]+s[0][1])+(s[0][2]+s[0][3]))
                     + ((s[1][0]+s[1][1])+(s[1][2]+s[1][3]))
                     + ((s[2][0]+s[2][1])+(s[2][2]+s[2][3]))
                     + ((s[3][0]+s[3][1])+(s[3][2]+s[3][3]));
            rs += __shfl_xor(rs, 16, 64);
            rs += __shfl_xor(rs, 32, 64);
            l_run += rs;
            u32x4 pw0, pw1;
            pw0[0] = cvtpk(s[0][0], s[0][1]); pw0[1] = cvtpk(s[0][2], s[0][3]);
            pw0[2] = cvtpk(s[1][0], s[1][1]); pw0[3] = cvtpk(s[1][2], s[1][3]);
            pw1[0] = cvtpk(s[2][0], s[2][1]); pw1[1] = cvtpk(s[2][2], s[2][3]);
            pw1[2] = cvtpk(s[3][0], s[3][1]); pw1[3] = cvtpk(s[3][2], s[3][3]);
            const bf16x8 pa0 = __builtin_bit_cast(bf16x8, pw0);
            const bf16x8 pa1 = __builtin_bit_cast(bf16x8, pw1);
            #pragma unroll
            for (int dt = 0; dt < 4; ++dt) {
                const int d = dt * 16 + li;
                bf16x8 v0 = *(const bf16x8*)&Vlds[cur][d][(g * 8) ^ swz(d)];
                bf16x8 v1 = *(const bf16x8*)&Vlds[cur][d][(32 + g * 8) ^ swz(d)];
                o[dt] = __builtin_amdgcn_mfma_f32_16x16x32_bf16(pa0, v0, o[dt], 0, 0, 0);
                o[dt] = __builtin_amdgcn_mfma_f32_16x16x32_bf16(pa1, v1, o[dt], 0, 0, 0);
            }
        }

        if (more) {
            __syncthreads();
            #pragma unroll
            for (int c = 0; c < 4; ++c) bc[c] = bn[c];
        }
    }

    if (WRITE_WS) {
        #pragma unroll
        for (int j = 0; j < 4; ++j) {
            const int lgq = qw + g * 4 + j;
            float* op = OutOrO + (((size_t)(b * NL + lgq)) * NH + h) * ND + li;
            op[0]  = o[0][j];
            op[16] = o[1][j];
            op[32] = o[2][j];
            op[48] = o[3][j];
        }
        if (g == 0) {
            const size_t rh = ((size_t)(b * NL + qw + li)) * NH + h;
            Mp[rh] = m_run;
            Lp[rh] = l_run;
        }
    } else {
        #pragma unroll
        for (int j = 0; j < 4; ++j) {
            const float lj = bpermf(g * 20 + j, l_run);
            const float inv = 1.0f / lj;
            const int lgq = qw + g * 4 + j;
            float* op = OutOrO + (((size_t)(b * NL + lgq)) * NH + h) * ND + li;
            op[0]  = o[0][j] * inv;
            op[16] = o[1][j] * inv;
            op[32] = o[2][j] * inv;
            op[48] = o[3][j] * inv;
        }
    }
}

// ---- split kernel: 1536 blocks = 48 segs (heavy-ish first) x 32 bh ----
__global__ __launch_bounds__(256)
void fa_part(const float* __restrict__ Q, const float* __restrict__ K,
             const float* __restrict__ V, const float* __restrict__ Bias,
             float* __restrict__ Ws)
{
    const int id = blockIdx.x;
    const int bh = id & 31, k = id >> 5;      // k = 0..47
    const int b  = bh >> 3, h = bh & 7;
    int qc, s;
    if (k < 16)      { qc = 31 - k;        s = 0; }   // long segs of big chunks
    else if (k < 32) { qc = 31 - (k - 16); s = 1; }   // tails of big chunks
    else             { qc = 47 - k;        s = 0; }   // small chunks (<=16 tiles)
    const int qb = qc << 6;
    const int t0 = s << 4;
    const int t1 = min((s + 1) << 4, qc + 1);

    float* Op = Ws + (size_t)s * OPH;
    float* Mp = Ws + 2 * (size_t)OPH + (size_t)s * MLH;
    float* Lp = Ws + 2 * (size_t)OPH + 2 * (size_t)MLH + (size_t)s * MLH;
    fa_core<true>(Q, K, V, Bias, Op, Mp, Lp, b, h, qb, t0, t1);
}

// ---- merge kernel: float4-vectorized combine (1 or 2 slots per row) ----
__global__ __launch_bounds__(256)
void fa_merge(const float* __restrict__ Ws, float* __restrict__ Out)
{
    const int gid  = blockIdx.x * 256 + threadIdx.x;   // 0 .. OPH/4-1
    const int base = gid << 2;
    const int rh   = base >> 6;                        // (b*NL+l)*NH+h
    const int lrow = (rh >> 3) & (NL - 1);
    const int qc   = lrow >> 6;
    const float* Mp = Ws + 2 * (size_t)OPH;
    const float* Lp = Ws + 2 * (size_t)OPH + 2 * (size_t)MLH;
    const f32x4 o1 = *(const f32x4*)(Ws + base);
    const float m1 = Mp[rh], l1 = Lp[rh];
    f32x4 r;
    if (qc < 16) {
        const float inv = 1.0f / l1;
        r = o1 * inv;
    } else {
        const f32x4 o2 = *(const f32x4*)(Ws + OPH + base);
        const float m2 = Mp[MLH + rh], l2 = Lp[MLH + rh];
        const float mm = fmaxf(m1, m2);
        const float c1 = exp2f(m1 - mm), c2 = exp2f(m2 - mm);
        const float inv = 1.0f / (c1 * l1 + c2 * l2);
        #pragma unroll
        for (int e = 0; e < 4; ++e) r[e] = (c1 * o1[e] + c2 * o2[e]) * inv;
    }
    *(f32x4*)(Out + base) = r;
}

// ---- fallback (ws too small): single kernel, 1024 blocks, full ranges ----
__global__ __launch_bounds__(256)
void fa_fwd_single(const float* __restrict__ Q, const float* __restrict__ K,
                   const float* __restrict__ V, const float* __restrict__ Bias,
                   float* __restrict__ Out)
{
    const int id = blockIdx.x;
    const int bh = id & 31, qc = 31 - (id >> 5);
    const int b  = bh >> 3, h = bh & 7;
    const int qb = qc << 6;
    fa_core<false>(Q, K, V, Bias, Out, nullptr, nullptr, b, h, qb, 0, qc + 1);
}

extern "C" void kernel_launch(void* const* d_in, const int* in_sizes, int n_in,
                              void* d_out, int out_size, void* d_ws, size_t ws_size,
                              hipStream_t stream)
{
    const float* Q    = (const float*)d_in[0];
    const float* K    = (const float*)d_in[1];
    const float* V    = (const float*)d_in[2];
    const float* Bias = (const float*)d_in[3];
    float* Out = (float*)d_out;

    const size_t need = ((size_t)2 * OPH + 4 * (size_t)MLH) * sizeof(float);  // ~34.6 MB
    if (ws_size >= need) {
        float* Ws = (float*)d_ws;
        fa_part <<<dim3(1536), dim3(256), 0, stream>>>(Q, K, V, Bias, Ws);
        fa_merge<<<dim3(OPH / 1024), dim3(256), 0, stream>>>(Ws, Out);
    } else {
        fa_fwd_single<<<dim3(1024), dim3(256), 0, stream>>>(Q, K, V, Bias, Out);
    }
}